// Round 10
// baseline (506.873 us; speedup 1.0000x reference)
//
#include <hip/hip_runtime.h>
#include <cstdint>

#define DEV __device__ __forceinline__

static constexpr float INV_SQRT_W = 0.04419417382415922f; // 1/sqrt(512)

typedef _Float16 half8 __attribute__((ext_vector_type(8)));
typedef float    f32x4 __attribute__((ext_vector_type(4)));

#define GLL16(g, l) __builtin_amdgcn_global_load_lds( \
    (const __attribute__((address_space(1))) void*)(g), \
    (__attribute__((address_space(3))) void*)(l), 16, 0, 0)

DEV int imax(int a, int b) { return a > b ? a : b; }
DEV int imin(int a, int b) { return a < b ? a : b; }

// styles[n][c] = w[n]·aw[c] / sqrt(512) + ab[c]
__global__ __launch_bounds__(256) void k_styles(const float* __restrict__ w,
    const float* __restrict__ aw, const float* __restrict__ ab,
    float* __restrict__ styles) {
  int t = blockIdx.x * 256 + threadIdx.x;        // 4096
  int n = t >> 9, c = t & 511;
  const float* wr = w + n * 512;
  const float* ar = aw + c * 512;
  float s = 0.f;
  for (int k = 0; k < 512; ++k) s = fmaf(wr[k], ar[k], s);
  styles[t] = s * INV_SQRT_W + ab[c];
}

// wsq[o][i] = sum_k w[o,i,k]^2 ; wscale[o] = rsqrt(mean over 4608)
__global__ __launch_bounds__(256) void k_wstats(const float* __restrict__ cw,
    float* __restrict__ wsq, float* __restrict__ wscale) {
  int o = blockIdx.x;
  __shared__ float red[256];
  float tot = 0.f;
  for (int i = threadIdx.x; i < 512; i += 256) {
    const float* p = cw + (o * 512 + i) * 9;
    float s = 0.f;
#pragma unroll
    for (int k = 0; k < 9; ++k) s = fmaf(p[k], p[k], s);
    wsq[o * 512 + i] = s;
    tot += s;
  }
  red[threadIdx.x] = tot;
  __syncthreads();
  for (int st = 128; st > 0; st >>= 1) {
    if (threadIdx.x < st) red[threadIdx.x] += red[threadIdx.x + st];
    __syncthreads();
  }
  if (threadIdx.x == 0) wscale[o] = rsqrtf(red[0] / 4608.f);
}

// sg = rsqrt(mean(styles^2)) over all 4096
__global__ __launch_bounds__(256) void k_sg(const float* __restrict__ styles,
                                            float* __restrict__ sg) {
  __shared__ float red[256];
  float s = 0.f;
  for (int t = threadIdx.x; t < 4096; t += 256) { float v = styles[t]; s = fmaf(v, v, s); }
  red[threadIdx.x] = s;
  __syncthreads();
  for (int st = 128; st > 0; st >>= 1) {
    if (threadIdx.x < st) red[threadIdx.x] += red[threadIdx.x + st];
    __syncthreads();
  }
  if (threadIdx.x == 0) sg[0] = rsqrtf(red[0] / 4096.f);
}

// coef[n][o] = ig * rsqrt(a^2*Q + 1e-8), a = wscale[o]*sg
__global__ __launch_bounds__(256) void k_coef(const float* __restrict__ styles,
    const float* __restrict__ wsq, const float* __restrict__ wscale,
    const float* __restrict__ sg, const float* __restrict__ ema,
    float* __restrict__ coef) {
  int n = blockIdx.x >> 1;
  int o = ((blockIdx.x & 1) << 8) + threadIdx.x;
  __shared__ float s2[512];
  for (int i = threadIdx.x; i < 512; i += 256) { float v = styles[n * 512 + i]; s2[i] = v * v; }
  __syncthreads();
  const float* wq = wsq + o * 512;
  float Q = 0.f;
  for (int i = 0; i < 512; ++i) Q = fmaf(s2[i], wq[i], Q);
  float a = wscale[o] * sg[0];
  float ig = rsqrtf(ema[0]);
  coef[n * 512 + o] = ig * rsqrtf(a * a * Q + 1e-8f);
}

// xT[n][ic][r][c][slot s][j] = f16( x[n, ic*32 + (s^sig(r,c))*8+j, r, c] * styles * sg )
// sig(r,c) = ((r*68 + c + 2) >> 1) & 3  -- bank swizzle baked (R4-verified layout)
__global__ __launch_bounds__(256) void k_xprep(const float* __restrict__ x,
    const float* __restrict__ styles, const float* __restrict__ sg,
    _Float16* __restrict__ xT) {
  const int b = blockIdx.x;                 // 8*16*64 = 8192
  const int r = b & 63, ic = (b >> 6) & 15, n = b >> 10;
  const int tid = threadIdx.x;
  const int c = tid >> 2, s = tid & 3;
  const float sgv = sg[0];
  const int sig = ((r * 68 + c + 2) >> 1) & 3;
  const int i0 = ic * 32 + (s ^ sig) * 8;
  half8 v;
#pragma unroll
  for (int j = 0; j < 8; ++j) {
    int i = i0 + j;
    float xv = x[(((size_t)n * 512 + i) * 64 + r) * 64 + c];
    v[j] = (_Float16)(xv * styles[n * 512 + i] * sgv);
  }
  *(half8*)(xT + ((((size_t)(n * 16 + ic) * 64 + r) * 64 + c) * 32) + s * 8) = v;
}

// w2[k9][ic][o][iw] = f16( cw[o, ic*32+iw, k9] * wscale[o] )
__global__ __launch_bounds__(256) void k_wprep(const float* __restrict__ cw,
    const float* __restrict__ wscale, _Float16* __restrict__ w2) {
  int t = blockIdx.x * 256 + threadIdx.x;    // 294912 slots of 8 halfs
  int s = t & 3;
  int o = (t >> 2) & 511;
  int ic = (t >> 11) & 15;
  int k9 = t >> 15;                          // 0..8
  float wsc = wscale[o];
  half8 v;
#pragma unroll
  for (int j = 0; j < 8; ++j) {
    int i = ic * 32 + s * 8 + j;
    v[j] = (_Float16)(cw[((size_t)o * 512 + i) * 9 + k9] * wsc);
  }
  *(half8*)(w2 + (size_t)t * 8) = v;
}

// Implicit-GEMM conv via MFMA f16 (R9 structure + explicit fragment pipeline).
// Block: 128 o x 128 p, 4 waves (2x2) of 64x64. B from double-buffered LDS patch
// (global_load_lds), A streamed from global (L2-resident via ot-major XCD swizzle).
// Inner loop: named aC/bC <-> aN/bN rotation, loads for stage k9+1 issued before
// MFMAs of stage k9, sched_barrier(0) pins the boundary -> counted waitcnts.
__global__ __launch_bounds__(256, 3) void k_conv(
    const _Float16* __restrict__ xT, const _Float16* __restrict__ w2,
    const float* __restrict__ coef, _Float16* __restrict__ convout) {
  // ot-major XCD swizzle: xcd k = b&7 -> ot = k>>1, nh = k&1; j = b>>3 in [0,140)
  const int b = blockIdx.x;
  const int kx = b & 7;
  const int j = b >> 3;
  const int ot = kx >> 1;
  const int n = (kx & 1) * 4 + j / 35;
  const int pt = j % 35;
  const int p0 = pt * 128;
  const int R0 = p0 / 66;
  const int oBase = ot * 128;

  const int tid = threadIdx.x;
  const int wave = tid >> 6;
  const int lane = tid & 63;
  const int wo = wave >> 1, wp = wave & 1;
  const int isub = lane >> 4;
  const int l15 = lane & 15;

  __shared__ _Float16 patch[2][10880];   // [5][68][32] halfs each, 21760 B per buf

  int rloc[4], rr2[4], cc[4]; bool valid[4];
#pragma unroll
  for (int nt = 0; nt < 4; ++nt) {
    int p = p0 + wp * 64 + nt * 16 + l15;
    valid[nt] = (p < 4356);
    if (!valid[nt]) p = 4355;
    int r = p / 66;
    rloc[nt] = r - R0;            // 0..2
    rr2[nt] = r - 2;              // input-row base (dr=0)
    cc[nt] = p - r * 66;
  }

  f32x4 acc[4][4];
#pragma unroll
  for (int mt = 0; mt < 4; ++mt)
#pragma unroll
    for (int nt = 0; nt < 4; ++nt) acc[mt][nt] = (f32x4){0.f, 0.f, 0.f, 0.f};

  const int oA = oBase + wo * 64 + l15;
  const _Float16* wp0 = w2 + (size_t)oA * 32 + isub * 8;

  // ---- hoisted halo zeroing: identical for every ic; both buffers ----
#pragma unroll
  for (int buf = 0; buf < 2; ++buf) {
    _Float16* dst = &patch[buf][0];
    if (tid < 80) {                       // side pad cols: 5 rows x {0,1,66,67} x 4 slots
      int pix = tid >> 2, s = tid & 3;
      int rl = pix >> 2, ci = pix & 3;
      int cl = (ci < 2) ? ci : (ci + 64);
      half8 z = {};
      *(half8*)(dst + (rl * 68 + cl) * 32 + s * 8) = z;
    }
#pragma unroll
    for (int rl = 0; rl < 5; ++rl) {
      int rin = R0 - 2 + rl;
      if (rin < 0 || rin >= 64) {
        for (int u = tid; u < 272; u += 256) {   // full out-of-range row
          half8 z = {};
          *(half8*)(dst + rl * 68 * 32 + u * 8) = z;
        }
      }
    }
  }

  // per-ic staging: 5 pure global_load_lds rows (interior only)
  auto stage_rows = [&](int ic, int buf) {
    const _Float16* src = xT + ((size_t)(n * 16 + ic) * 4096) * 32;
    _Float16* dst = &patch[buf][0];
#pragma unroll
    for (int rl = 0; rl < 5; ++rl) {
      int rin = R0 - 2 + rl;
      if (rin >= 0 && rin < 64)
        GLL16(src + (size_t)rin * 2048 + tid * 8, dst + (rl * 68 + 2) * 32 + tid * 8);
    }
  };

  auto LOADA = [&](half8 (&a)[4], int k9, int ic) {
#pragma unroll
    for (int mt = 0; mt < 4; ++mt)
      a[mt] = *(const half8*)(wp0 + ((size_t)(k9 * 16 + ic) * 512 + mt * 16) * 32);
  };
  auto LOADB = [&](half8 (&b8)[4], int k9, const _Float16* pb) {
    const int dr = k9 / 3, dc = k9 % 3;
#pragma unroll
    for (int nt = 0; nt < 4; ++nt) {
      int rl = rloc[nt] + dr;
      int cl = cc[nt] + dc;
      int sig = (((rr2[nt] + dr) * 68 + cl) >> 1) & 3;
      b8[nt] = *(const half8*)(pb + (rl * 68 + cl) * 32 + ((isub ^ sig) << 3));
    }
  };
  auto MFMA16 = [&](half8 (&a)[4], half8 (&b8)[4]) {
#pragma unroll
    for (int nt = 0; nt < 4; ++nt)
#pragma unroll
      for (int mt = 0; mt < 4; ++mt)
        acc[mt][nt] = __builtin_amdgcn_mfma_f32_16x16x32_f16(a[mt], b8[nt], acc[mt][nt], 0, 0, 0);
  };

  stage_rows(0, 0);
  __syncthreads();

  half8 aC[4], bC[4], aN[4], bN[4];
  for (int ic = 0; ic < 16; ++ic) {
    const int buf = ic & 1;
    if (ic < 15) stage_rows(ic + 1, buf ^ 1);
    const _Float16* pb = &patch[buf][0];

    LOADA(aC, 0, ic); LOADB(bC, 0, pb);
#pragma unroll
    for (int kk = 0; kk < 4; ++kk) {
      const int k9b = 2 * kk + 1;
      LOADA(aN, k9b, ic); LOADB(bN, k9b, pb);
      __builtin_amdgcn_sched_barrier(0);
      MFMA16(aC, bC);                              // stage 2kk
      if (k9b < 8) { LOADA(aC, k9b + 1, ic); LOADB(bC, k9b + 1, pb); }
      __builtin_amdgcn_sched_barrier(0);
      MFMA16(aN, bN);                              // stage 2kk+1
    }
    MFMA16(aC, bC);                                // stage 8
    __syncthreads();
  }

  // epilogue: C layout col=l15 (p), row=isub*4+j (o); scale by coef; f16 store
#pragma unroll
  for (int mt = 0; mt < 4; ++mt) {
    const int o = oBase + wo * 64 + mt * 16 + isub * 4;
#pragma unroll
    for (int jj = 0; jj < 4; ++jj) {
      const float cf = coef[n * 512 + o + jj];
      _Float16* outp = convout + (size_t)(n * 512 + o + jj) * 4356;
#pragma unroll
      for (int nt = 0; nt < 4; ++nt) {
        if (valid[nt]) {
          int p = p0 + wp * 64 + nt * 16 + l15;
          outp[p] = (_Float16)(acc[mt][nt][jj] * cf);
        }
      }
    }
  }
}

// Fused bias + up-FIR(x2, polyphase) + lrelu + clamp + down-FIR(/2).
// NO cross-lane LDS sharing (R3 lesson). Verified formulas, 32-row tile, f16 in.
__global__ __launch_bounds__(256) void k_flrelu(const _Float16* __restrict__ convout,
    const float* __restrict__ cbias, const float* __restrict__ fu,
    const float* __restrict__ fd, float* __restrict__ out) {
  const int img = blockIdx.x >> 1;       // n*512+c
  const int tile = blockIdx.x & 1;
  const int P0 = tile * 32;              // output rows [P0, P0+32)
  const int c = img & 511;
  const int tid = threadIdx.x;
  const int wv = tid >> 6, ln = tid & 63;

  __shared__ float As[42 * 68];          // conv rows P0-4 .. P0+37 (+bias), 0 outside
  __shared__ float Bs[74 * 76];          // v-up rows, col offset +4, zero aprons
  __shared__ float Vs[74 * 64];          // after horizontal up+lrelu+down

  float fupr[12], fdr[12];
#pragma unroll
  for (int jj = 0; jj < 12; ++jj) { fupr[jj] = fu[jj]; fdr[jj] = fd[11 - jj]; }

  // stage 1: A rows [P0-4, P0+37] + bias; zero outside image
  {
    const _Float16* src = convout + (size_t)img * 4356;
    const float bias = cbias[c];
    for (int t = tid; t < 42 * 68; t += 256) {
      int r = t / 68, cc2 = t - r * 68;
      int gr = P0 - 4 + r;
      float v = 0.f;
      if (cc2 < 66 && gr >= 0 && gr < 66) v = (float)src[gr * 66 + cc2] + bias;
      As[t] = v;
    }
  }
  __syncthreads();

  // stage 2: vertical up-FIR, polyphase 6 taps
  for (int t = tid; t < 74 * 33; t += 256) {
    int kk2 = t / 33, m2 = t - kk2 * 33;
    int e = kk2 & 1, kk = (kk2 - e) >> 1;
    const float* Ab = &As[kk * 68 + 2 * m2];
    float sx = 0.f, sy = 0.f;
#pragma unroll
    for (int jj = 0; jj < 6; ++jj) {
      float2 a = *(const float2*)(Ab + (5 - jj) * 68);
      float f = e ? fupr[2 * jj + 1] : fupr[2 * jj];
      sx = fmaf(f, a.x, sx);
      sy = fmaf(f, a.y, sy);
    }
    float2 s2v = make_float2(sx, sy);
    *(float2*)&Bs[kk2 * 76 + 4 + 2 * m2] = s2v;
  }
  for (int t = tid; t < 74 * 10; t += 256) {
    int kk2 = t / 10, ci = t - kk2 * 10;
    int col = (ci < 4) ? ci : (66 + ci);
    Bs[kk2 * 76 + col] = 0.f;
  }
  __syncthreads();

  // stage 3: per-lane recompute of upsampled row + lrelu + horizontal down
  for (int kk2 = wv; kk2 < 74; kk2 += 4) {
    const float* Br = &Bs[kk2 * 76 + ln];
    float bb2[11];
#pragma unroll
    for (int t = 0; t < 11; ++t) bb2[t] = Br[t];
    float v = 0.f;
#pragma unroll
    for (int d = 0; d < 6; ++d) {
      float ue = 0.f, uo = 0.f;
#pragma unroll
      for (int jj = 0; jj < 6; ++jj) {
        float bb = bb2[d + 5 - jj];
        ue = fmaf(fupr[2 * jj], bb, ue);
        uo = fmaf(fupr[2 * jj + 1], bb, uo);
      }
      ue *= (ue >= 0.f) ? 5.65685424949238f : 1.13137084989848f;
      uo *= (uo >= 0.f) ? 5.65685424949238f : 1.13137084989848f;
      ue = fminf(256.f, fmaxf(-256.f, ue));
      uo = fminf(256.f, fmaxf(-256.f, uo));
      v = fmaf(fdr[2 * d], ue, v);
      v = fmaf(fdr[2 * d + 1], uo, v);
    }
    Vs[kk2 * 64 + ln] = v;
  }
  __syncthreads();

  // stage 4: vertical down-FIR -> out rows [P0, P0+32)
  for (int t = tid; t < 2048; t += 256) {
    int pr = t >> 6, q = t & 63;
    const float* Vb = &Vs[2 * pr * 64 + q];
    float s = 0.f;
#pragma unroll
    for (int jj = 0; jj < 12; ++jj) s = fmaf(fdr[jj], Vb[jj * 64], s);
    out[(size_t)img * 4096 + (P0 + pr) * 64 + q] = s;
  }
}

extern "C" void kernel_launch(void* const* d_in, const int* in_sizes, int n_in,
                              void* d_out, int out_size, void* d_ws, size_t ws_size,
                              hipStream_t stream) {
  const float* x   = (const float*)d_in[0];
  const float* w   = (const float*)d_in[1];
  const float* aw  = (const float*)d_in[2];
  const float* ab  = (const float*)d_in[3];
  const float* cw  = (const float*)d_in[4];
  const float* cb  = (const float*)d_in[5];
  const float* fu  = (const float*)d_in[6];
  const float* fd  = (const float*)d_in[7];
  const float* ema = (const float*)d_in[8];
  float* out = (float*)d_out;

  float* ws       = (float*)d_ws;
  float* styles   = ws;                         // 4096
  float* wsq      = styles + 4096;              // 262144
  float* wscale   = wsq + 262144;               // 512
  float* coef     = wscale + 512;               // 4096
  float* sg       = coef + 4096;                // 8
  _Float16* convout = (_Float16*)(sg + 8);      // 17,842,176 halfs
  _Float16* xT    = convout + 17842176;         // 16,777,216 halfs (R4 layout 64x64)
  _Float16* w2    = xT + 16777216;              // 2,359,296 halfs

  k_styles<<<16, 256, 0, stream>>>(w, aw, ab, styles);
  k_sg<<<1, 256, 0, stream>>>(styles, sg);
  k_wstats<<<512, 256, 0, stream>>>(cw, wsq, wscale);
  k_coef<<<16, 256, 0, stream>>>(styles, wsq, wscale, sg, ema, coef);
  k_xprep<<<8192, 256, 0, stream>>>(x, styles, sg, xT);
  k_wprep<<<1152, 256, 0, stream>>>(cw, wscale, w2);
  k_conv<<<1120, 256, 0, stream>>>(xT, w2, coef, convout);
  k_flrelu<<<8192, 256, 0, stream>>>(convout, cb, fu, fd, out);
}

// Round 11
// 461.155 us; speedup vs baseline: 1.0991x; 1.0991x over previous
//
#include <hip/hip_runtime.h>
#include <cstdint>

#define DEV __device__ __forceinline__

static constexpr float INV_SQRT_W = 0.04419417382415922f; // 1/sqrt(512)

typedef _Float16 half8 __attribute__((ext_vector_type(8)));
typedef float    f32x4 __attribute__((ext_vector_type(4)));

#define GLL16(g, l) __builtin_amdgcn_global_load_lds( \
    (const __attribute__((address_space(1))) void*)(g), \
    (__attribute__((address_space(3))) void*)(l), 16, 0, 0)

DEV int imax(int a, int b) { return a > b ? a : b; }
DEV int imin(int a, int b) { return a < b ? a : b; }

// styles[n][c] = w[n]·aw[c] / sqrt(512) + ab[c]
__global__ __launch_bounds__(256) void k_styles(const float* __restrict__ w,
    const float* __restrict__ aw, const float* __restrict__ ab,
    float* __restrict__ styles) {
  int t = blockIdx.x * 256 + threadIdx.x;        // 4096
  int n = t >> 9, c = t & 511;
  const float* wr = w + n * 512;
  const float* ar = aw + c * 512;
  float s = 0.f;
  for (int k = 0; k < 512; ++k) s = fmaf(wr[k], ar[k], s);
  styles[t] = s * INV_SQRT_W + ab[c];
}

// wsq[o][i] = sum_k w[o,i,k]^2 ; wscale[o] = rsqrt(mean over 4608)
__global__ __launch_bounds__(256) void k_wstats(const float* __restrict__ cw,
    float* __restrict__ wsq, float* __restrict__ wscale) {
  int o = blockIdx.x;
  __shared__ float red[256];
  float tot = 0.f;
  for (int i = threadIdx.x; i < 512; i += 256) {
    const float* p = cw + (o * 512 + i) * 9;
    float s = 0.f;
#pragma unroll
    for (int k = 0; k < 9; ++k) s = fmaf(p[k], p[k], s);
    wsq[o * 512 + i] = s;
    tot += s;
  }
  red[threadIdx.x] = tot;
  __syncthreads();
  for (int st = 128; st > 0; st >>= 1) {
    if (threadIdx.x < st) red[threadIdx.x] += red[threadIdx.x + st];
    __syncthreads();
  }
  if (threadIdx.x == 0) wscale[o] = rsqrtf(red[0] / 4608.f);
}

// sg = rsqrt(mean(styles^2)) over all 4096
__global__ __launch_bounds__(256) void k_sg(const float* __restrict__ styles,
                                            float* __restrict__ sg) {
  __shared__ float red[256];
  float s = 0.f;
  for (int t = threadIdx.x; t < 4096; t += 256) { float v = styles[t]; s = fmaf(v, v, s); }
  red[threadIdx.x] = s;
  __syncthreads();
  for (int st = 128; st > 0; st >>= 1) {
    if (threadIdx.x < st) red[threadIdx.x] += red[threadIdx.x + st];
    __syncthreads();
  }
  if (threadIdx.x == 0) sg[0] = rsqrtf(red[0] / 4096.f);
}

// coef[n][o] = ig * rsqrt(a^2*Q + 1e-8), a = wscale[o]*sg
__global__ __launch_bounds__(256) void k_coef(const float* __restrict__ styles,
    const float* __restrict__ wsq, const float* __restrict__ wscale,
    const float* __restrict__ sg, const float* __restrict__ ema,
    float* __restrict__ coef) {
  int n = blockIdx.x >> 1;
  int o = ((blockIdx.x & 1) << 8) + threadIdx.x;
  __shared__ float s2[512];
  for (int i = threadIdx.x; i < 512; i += 256) { float v = styles[n * 512 + i]; s2[i] = v * v; }
  __syncthreads();
  const float* wq = wsq + o * 512;
  float Q = 0.f;
  for (int i = 0; i < 512; ++i) Q = fmaf(s2[i], wq[i], Q);
  float a = wscale[o] * sg[0];
  float ig = rsqrtf(ema[0]);
  coef[n * 512 + o] = ig * rsqrtf(a * a * Q + 1e-8f);
}

// xT[n][ic][r][c][slot s][j] = f16( x[n, ic*32 + (s^sig(r,c))*8+j, r, c] * styles * sg )
// sig(r,c) = ((r*68 + c + 2) >> 1) & 3  -- bank swizzle baked (R4-verified layout)
__global__ __launch_bounds__(256) void k_xprep(const float* __restrict__ x,
    const float* __restrict__ styles, const float* __restrict__ sg,
    _Float16* __restrict__ xT) {
  const int b = blockIdx.x;                 // 8*16*64 = 8192
  const int r = b & 63, ic = (b >> 6) & 15, n = b >> 10;
  const int tid = threadIdx.x;
  const int c = tid >> 2, s = tid & 3;
  const float sgv = sg[0];
  const int sig = ((r * 68 + c + 2) >> 1) & 3;
  const int i0 = ic * 32 + (s ^ sig) * 8;
  half8 v;
#pragma unroll
  for (int j = 0; j < 8; ++j) {
    int i = i0 + j;
    float xv = x[(((size_t)n * 512 + i) * 64 + r) * 64 + c];
    v[j] = (_Float16)(xv * styles[n * 512 + i] * sgv);
  }
  *(half8*)(xT + ((((size_t)(n * 16 + ic) * 64 + r) * 64 + c) * 32) + s * 8) = v;
}

// w2[k9][ic][o][iw] = f16( cw[o, ic*32+iw, k9] * wscale[o] )
__global__ __launch_bounds__(256) void k_wprep(const float* __restrict__ cw,
    const float* __restrict__ wscale, _Float16* __restrict__ w2) {
  int t = blockIdx.x * 256 + threadIdx.x;    // 294912 slots of 8 halfs
  int s = t & 3;
  int o = (t >> 2) & 511;
  int ic = (t >> 11) & 15;
  int k9 = t >> 15;                          // 0..8
  float wsc = wscale[o];
  half8 v;
#pragma unroll
  for (int j = 0; j < 8; ++j) {
    int i = ic * 32 + s * 8 + j;
    v[j] = (_Float16)(cw[((size_t)o * 512 + i) * 9 + k9] * wsc);
  }
  *(half8*)(w2 + (size_t)t * 8) = v;
}

// Implicit-GEMM conv via MFMA f16 (R9-verified inner loop; SINGLE LDS buffer for
// occupancy: 21.76 KB -> ~6 blocks/CU, whole 1120-block grid resident in one round).
// B from LDS patch (global_load_lds), A streamed from global (L2-resident via
// ot-major XCD swizzle). Staging latency exposed per ic but covered by block TLP.
__global__ __launch_bounds__(256, 3) void k_conv(
    const _Float16* __restrict__ xT, const _Float16* __restrict__ w2,
    const float* __restrict__ coef, _Float16* __restrict__ convout) {
  // ot-major XCD swizzle: xcd k = b&7 -> ot = k>>1, nh = k&1; j = b>>3 in [0,140)
  const int b = blockIdx.x;
  const int kx = b & 7;
  const int j = b >> 3;
  const int ot = kx >> 1;
  const int n = (kx & 1) * 4 + j / 35;
  const int pt = j % 35;
  const int p0 = pt * 128;
  const int R0 = p0 / 66;
  const int oBase = ot * 128;

  const int tid = threadIdx.x;
  const int wave = tid >> 6;
  const int lane = tid & 63;
  const int wo = wave >> 1, wp = wave & 1;
  const int isub = lane >> 4;
  const int l15 = lane & 15;

  __shared__ _Float16 patch[10880];   // [5][68][32] halfs, 21760 B (single buffer)

  int rloc[4], rr2[4], cc[4]; bool valid[4];
#pragma unroll
  for (int nt = 0; nt < 4; ++nt) {
    int p = p0 + wp * 64 + nt * 16 + l15;
    valid[nt] = (p < 4356);
    if (!valid[nt]) p = 4355;
    int r = p / 66;
    rloc[nt] = r - R0;            // 0..2
    rr2[nt] = r - 2;              // input-row base (dr=0)
    cc[nt] = p - r * 66;
  }

  f32x4 acc[4][4];
#pragma unroll
  for (int mt = 0; mt < 4; ++mt)
#pragma unroll
    for (int nt = 0; nt < 4; ++nt) acc[mt][nt] = (f32x4){0.f, 0.f, 0.f, 0.f};

  const int oA = oBase + wo * 64 + l15;
  const _Float16* wp0 = w2 + (size_t)oA * 32 + isub * 8;

  // ---- hoisted halo zeroing: identical for every ic ----
  {
    _Float16* dst = &patch[0];
    if (tid < 80) {                       // side pad cols: 5 rows x {0,1,66,67} x 4 slots
      int pix = tid >> 2, s = tid & 3;
      int rl = pix >> 2, ci = pix & 3;
      int cl = (ci < 2) ? ci : (ci + 64);
      half8 z = {};
      *(half8*)(dst + (rl * 68 + cl) * 32 + s * 8) = z;
    }
#pragma unroll
    for (int rl = 0; rl < 5; ++rl) {
      int rin = R0 - 2 + rl;
      if (rin < 0 || rin >= 64) {
        for (int u = tid; u < 272; u += 256) {   // full out-of-range row
          half8 z = {};
          *(half8*)(dst + rl * 68 * 32 + u * 8) = z;
        }
      }
    }
  }

  // per-ic staging: 5 pure global_load_lds rows (interior only)
  auto stage_rows = [&](int ic) {
    const _Float16* src = xT + ((size_t)(n * 16 + ic) * 4096) * 32;
    _Float16* dst = &patch[0];
#pragma unroll
    for (int rl = 0; rl < 5; ++rl) {
      int rin = R0 - 2 + rl;
      if (rin >= 0 && rin < 64)
        GLL16(src + (size_t)rin * 2048 + tid * 8, dst + (rl * 68 + 2) * 32 + tid * 8);
    }
  };

  stage_rows(0);
  __syncthreads();

  for (int ic = 0; ic < 16; ++ic) {
    const _Float16* pb = &patch[0];

#pragma unroll
    for (int k9 = 0; k9 < 9; ++k9) {
      const int dr = k9 / 3, dc = k9 % 3;
      half8 aF[4];
#pragma unroll
      for (int mt = 0; mt < 4; ++mt)
        aF[mt] = *(const half8*)(wp0 + ((size_t)(k9 * 16 + ic) * 512 + mt * 16) * 32);
#pragma unroll
      for (int nt = 0; nt < 4; ++nt) {
        int rl = rloc[nt] + dr;
        int cl = cc[nt] + dc;
        int sig = (((rr2[nt] + dr) * 68 + cl) >> 1) & 3;
        int ah = (rl * 68 + cl) * 32 + ((isub ^ sig) << 3);
        half8 bF = *(const half8*)(pb + ah);
#pragma unroll
        for (int mt = 0; mt < 4; ++mt)
          acc[mt][nt] = __builtin_amdgcn_mfma_f32_16x16x32_f16(aF[mt], bF, acc[mt][nt], 0, 0, 0);
      }
    }
    __syncthreads();                       // all waves done reading patch
    if (ic < 15) {
      stage_rows(ic + 1);
      __syncthreads();                     // staged data visible (vmcnt drained)
    }
  }

  // epilogue: C layout col=l15 (p), row=isub*4+j (o); scale by coef; f16 store
#pragma unroll
  for (int mt = 0; mt < 4; ++mt) {
    const int o = oBase + wo * 64 + mt * 16 + isub * 4;
#pragma unroll
    for (int jj = 0; jj < 4; ++jj) {
      const float cf = coef[n * 512 + o + jj];
      _Float16* outp = convout + (size_t)(n * 512 + o + jj) * 4356;
#pragma unroll
      for (int nt = 0; nt < 4; ++nt) {
        if (valid[nt]) {
          int p = p0 + wp * 64 + nt * 16 + l15;
          outp[p] = (_Float16)(acc[mt][nt][jj] * cf);
        }
      }
    }
  }
}

// Fused bias + up-FIR(x2, polyphase) + lrelu + clamp + down-FIR(/2).
// NO cross-lane LDS sharing (R3 lesson). Verified formulas, 32-row tile, f16 in.
__global__ __launch_bounds__(256) void k_flrelu(const _Float16* __restrict__ convout,
    const float* __restrict__ cbias, const float* __restrict__ fu,
    const float* __restrict__ fd, float* __restrict__ out) {
  const int img = blockIdx.x >> 1;       // n*512+c
  const int tile = blockIdx.x & 1;
  const int P0 = tile * 32;              // output rows [P0, P0+32)
  const int c = img & 511;
  const int tid = threadIdx.x;
  const int wv = tid >> 6, ln = tid & 63;

  __shared__ float As[42 * 68];          // conv rows P0-4 .. P0+37 (+bias), 0 outside
  __shared__ float Bs[74 * 76];          // v-up rows, col offset +4, zero aprons
  __shared__ float Vs[74 * 64];          // after horizontal up+lrelu+down

  float fupr[12], fdr[12];
#pragma unroll
  for (int jj = 0; jj < 12; ++jj) { fupr[jj] = fu[jj]; fdr[jj] = fd[11 - jj]; }

  // stage 1: A rows [P0-4, P0+37] + bias; zero outside image
  {
    const _Float16* src = convout + (size_t)img * 4356;
    const float bias = cbias[c];
    for (int t = tid; t < 42 * 68; t += 256) {
      int r = t / 68, cc2 = t - r * 68;
      int gr = P0 - 4 + r;
      float v = 0.f;
      if (cc2 < 66 && gr >= 0 && gr < 66) v = (float)src[gr * 66 + cc2] + bias;
      As[t] = v;
    }
  }
  __syncthreads();

  // stage 2: vertical up-FIR, polyphase 6 taps
  for (int t = tid; t < 74 * 33; t += 256) {
    int kk2 = t / 33, m2 = t - kk2 * 33;
    int e = kk2 & 1, kk = (kk2 - e) >> 1;
    const float* Ab = &As[kk * 68 + 2 * m2];
    float sx = 0.f, sy = 0.f;
#pragma unroll
    for (int jj = 0; jj < 6; ++jj) {
      float2 a = *(const float2*)(Ab + (5 - jj) * 68);
      float f = e ? fupr[2 * jj + 1] : fupr[2 * jj];
      sx = fmaf(f, a.x, sx);
      sy = fmaf(f, a.y, sy);
    }
    float2 s2v = make_float2(sx, sy);
    *(float2*)&Bs[kk2 * 76 + 4 + 2 * m2] = s2v;
  }
  for (int t = tid; t < 74 * 10; t += 256) {
    int kk2 = t / 10, ci = t - kk2 * 10;
    int col = (ci < 4) ? ci : (66 + ci);
    Bs[kk2 * 76 + col] = 0.f;
  }
  __syncthreads();

  // stage 3: per-lane recompute of upsampled row + lrelu + horizontal down
  for (int kk2 = wv; kk2 < 74; kk2 += 4) {
    const float* Br = &Bs[kk2 * 76 + ln];
    float bb2[11];
#pragma unroll
    for (int t = 0; t < 11; ++t) bb2[t] = Br[t];
    float v = 0.f;
#pragma unroll
    for (int d = 0; d < 6; ++d) {
      float ue = 0.f, uo = 0.f;
#pragma unroll
      for (int jj = 0; jj < 6; ++jj) {
        float bb = bb2[d + 5 - jj];
        ue = fmaf(fupr[2 * jj], bb, ue);
        uo = fmaf(fupr[2 * jj + 1], bb, uo);
      }
      ue *= (ue >= 0.f) ? 5.65685424949238f : 1.13137084989848f;
      uo *= (uo >= 0.f) ? 5.65685424949238f : 1.13137084989848f;
      ue = fminf(256.f, fmaxf(-256.f, ue));
      uo = fminf(256.f, fmaxf(-256.f, uo));
      v = fmaf(fdr[2 * d], ue, v);
      v = fmaf(fdr[2 * d + 1], uo, v);
    }
    Vs[kk2 * 64 + ln] = v;
  }
  __syncthreads();

  // stage 4: vertical down-FIR -> out rows [P0, P0+32)
  for (int t = tid; t < 2048; t += 256) {
    int pr = t >> 6, q = t & 63;
    const float* Vb = &Vs[2 * pr * 64 + q];
    float s = 0.f;
#pragma unroll
    for (int jj = 0; jj < 12; ++jj) s = fmaf(fdr[jj], Vb[jj * 64], s);
    out[(size_t)img * 4096 + (P0 + pr) * 64 + q] = s;
  }
}

extern "C" void kernel_launch(void* const* d_in, const int* in_sizes, int n_in,
                              void* d_out, int out_size, void* d_ws, size_t ws_size,
                              hipStream_t stream) {
  const float* x   = (const float*)d_in[0];
  const float* w   = (const float*)d_in[1];
  const float* aw  = (const float*)d_in[2];
  const float* ab  = (const float*)d_in[3];
  const float* cw  = (const float*)d_in[4];
  const float* cb  = (const float*)d_in[5];
  const float* fu  = (const float*)d_in[6];
  const float* fd  = (const float*)d_in[7];
  const float* ema = (const float*)d_in[8];
  float* out = (float*)d_out;

  float* ws       = (float*)d_ws;
  float* styles   = ws;                         // 4096
  float* wsq      = styles + 4096;              // 262144
  float* wscale   = wsq + 262144;               // 512
  float* coef     = wscale + 512;               // 4096
  float* sg       = coef + 4096;                // 8
  _Float16* convout = (_Float16*)(sg + 8);      // 17,842,176 halfs
  _Float16* xT    = convout + 17842176;         // 16,777,216 halfs (R4 layout 64x64)
  _Float16* w2    = xT + 16777216;              // 2,359,296 halfs

  k_styles<<<16, 256, 0, stream>>>(w, aw, ab, styles);
  k_sg<<<1, 256, 0, stream>>>(styles, sg);
  k_wstats<<<512, 256, 0, stream>>>(cw, wsq, wscale);
  k_coef<<<16, 256, 0, stream>>>(styles, wsq, wscale, sg, ema, coef);
  k_xprep<<<8192, 256, 0, stream>>>(x, styles, sg, xT);
  k_wprep<<<1152, 256, 0, stream>>>(cw, wscale, w2);
  k_conv<<<1120, 256, 0, stream>>>(xT, w2, coef, convout);
  k_flrelu<<<8192, 256, 0, stream>>>(convout, cb, fu, fd, out);
}